// Round 1
// baseline (995.844 us; speedup 1.0000x reference)
//
#include <hip/hip_runtime.h>
#include <hip/hip_bf16.h>

// Grouped conv2d as implicit GEMM per group:
//   out[b*64+co][h][w] = sum_{ci,kh,kw} W[b*64+co][ci][kh][kw] * x[b*64+ci][h+kh-1][w+kw-1]
// bf16 MFMA (16x16x32), fp32 accumulate. K = tap-major (9 taps x 64 ci).

typedef __bf16 bf16x8 __attribute__((ext_vector_type(8)));
typedef float  f32x4  __attribute__((ext_vector_type(4)));

#define NB 32
#define NCH 64
#define NH 256
#define NW 256
#define TILE_H 4
#define TILE_W 64
#define XROWS 6     // TILE_H + 2 (halo)
#define XCOLS 68    // TILE_W + 2, padded (cells 66,67 unused)

// ---------------------------------------------------------------------------
// Repack weights into MFMA A-fragment order:
//   pk[((b*9+tap)*4+mt)*2+kc][lane][j]  (bf16, 16B per lane)
// value = W[b*64 + mt*16 + (lane&15)][kc*32 + (lane>>4)*8 + j][tap]
// ---------------------------------------------------------------------------
__global__ void repack_weights_kernel(const float* __restrict__ wsrc,
                                      __bf16* __restrict__ pk) {
    int t = blockIdx.x * blockDim.x + threadIdx.x;
    if (t >= NB * 9 * 4 * 2 * 64) return;
    int lane = t & 63;
    int r = t >> 6;
    int kc = r & 1;  r >>= 1;
    int mt = r & 3;  r >>= 2;
    int tap = r % 9;
    int b   = r / 9;
    int co  = b * 64 + mt * 16 + (lane & 15);
    int ci0 = kc * 32 + (lane >> 4) * 8;
    bf16x8 v;
#pragma unroll
    for (int j = 0; j < 8; ++j) {
        v[j] = (__bf16)wsrc[(co * 64 + ci0 + j) * 9 + tap];
    }
    *reinterpret_cast<bf16x8*>(pk + (size_t)t * 8) = v;
}

// ---------------------------------------------------------------------------
// Main conv kernel. Block = (group b, 4 output rows, 64 output cols).
// 4 waves; wave w owns output row h0+w, all 64 c_out, 64 cols (4 n-tiles).
// X tile staged in LDS as bf16, layout [r][c][ci] with ci XOR-swizzled by
// (c&7)<<3 so B-fragment ds_read_b128 is bank-conflict-free (2-way only).
// A fragments read per-tap straight from repacked global (coalesced 16B/lane).
// ---------------------------------------------------------------------------
__launch_bounds__(256, 2)
__global__ void conv_mfma_kernel(const float* __restrict__ x,
                                 const __bf16* __restrict__ pk,
                                 float* __restrict__ out) {
    __shared__ __align__(16) __bf16 xs[XROWS * XCOLS * 64];

    const int b   = blockIdx.z;
    const int h0  = blockIdx.y * TILE_H;
    const int w0  = blockIdx.x * TILE_W;
    const int tid  = threadIdx.x;
    const int wid  = tid >> 6;
    const int lane = tid & 63;

    // ---- stage X halo tile: fp32 -> bf16, swizzled ----
    for (int p = wid; p < XROWS * 64; p += 4) {
        const int r  = p >> 6;        // 0..5
        const int ci = p & 63;
        const int h  = h0 - 1 + r;
        const bool hok = (unsigned)h < NH;
        const float* src = x + (((size_t)(b * 64 + ci) * NH + (hok ? h : 0)) * NW);
        {
            const int c = lane;                    // 0..63
            const int w = w0 - 1 + c;
            float f = (hok && (unsigned)w < NW) ? src[w] : 0.f;
            xs[(r * XCOLS + c) * 64 + (ci ^ ((c & 7) << 3))] = (__bf16)f;
        }
        if (lane < 2) {
            const int c = 64 + lane;               // 64,65
            const int w = w0 - 1 + c;
            float f = (hok && (unsigned)w < NW) ? src[w] : 0.f;
            xs[(r * XCOLS + c) * 64 + (ci ^ ((c & 7) << 3))] = (__bf16)f;
        }
    }

    f32x4 acc[4][4];   // [mt][q]
#pragma unroll
    for (int mt = 0; mt < 4; ++mt)
#pragma unroll
        for (int q = 0; q < 4; ++q)
            acc[mt][q] = (f32x4){0.f, 0.f, 0.f, 0.f};

    __syncthreads();

    const __bf16* pkb = pk + (size_t)b * 9 * 4096;
    const int nl   = lane & 15;
    const int kgrp = lane >> 4;       // 0..3

#pragma unroll 1
    for (int tap = 0; tap < 9; ++tap) {
        // A fragments for this tap: 8 x 16B coalesced global loads (L2/L3-hot)
        bf16x8 af[2][4];
        const __bf16* ap = pkb + tap * 4096;
#pragma unroll
        for (int kc = 0; kc < 2; ++kc)
#pragma unroll
            for (int mt = 0; mt < 4; ++mt)
                af[kc][mt] = *reinterpret_cast<const bf16x8*>(
                    ap + ((mt * 2 + kc) * 64 + lane) * 8);

        const int kh = tap / 3;
        const int kw = tap - kh * 3;
        const int rowbase = (wid + kh) * XCOLS;

#pragma unroll
        for (int kc = 0; kc < 2; ++kc) {
            const int ci0 = kc * 32 + kgrp * 8;
#pragma unroll
            for (int q = 0; q < 4; ++q) {
                const int c = q * 16 + nl + kw;    // 0..65
                bf16x8 bf = *reinterpret_cast<const bf16x8*>(
                    xs + (rowbase + c) * 64 + (ci0 ^ ((c & 7) << 3)));
#pragma unroll
                for (int mt = 0; mt < 4; ++mt)
                    acc[mt][q] = __builtin_amdgcn_mfma_f32_16x16x32_bf16(
                        af[kc][mt], bf, acc[mt][q], 0, 0, 0);
            }
        }
    }

    // ---- epilogue: D lane layout col=lane&15, row=(lane>>4)*4+reg ----
    const int mrow = (lane >> 4) * 4;
    const int h = h0 + wid;
#pragma unroll
    for (int mt = 0; mt < 4; ++mt) {
#pragma unroll
        for (int q = 0; q < 4; ++q) {
            const int w = w0 + q * 16 + nl;
#pragma unroll
            for (int rg = 0; rg < 4; ++rg) {
                const int co = mt * 16 + mrow + rg;
                out[((size_t)(b * 64 + co) * NH + h) * NW + w] = acc[mt][q][rg];
            }
        }
    }
}

extern "C" void kernel_launch(void* const* d_in, const int* in_sizes, int n_in,
                              void* d_out, int out_size, void* d_ws, size_t ws_size,
                              hipStream_t stream) {
    const float* x = (const float*)d_in[0];     // [1, 32*64, 256, 256] fp32
    const float* w = (const float*)d_in[1];     // [2048, 64, 3, 3] fp32
    float* out = (float*)d_out;                 // [1, 2048, 256, 256] fp32
    __bf16* pk = (__bf16*)d_ws;                 // 2.25 MB repacked bf16 weights

    // 1) repack weights (runs every call; deterministic)
    {
        int total = NB * 9 * 4 * 2 * 64;        // 147456
        int blk = 256;
        int grid = (total + blk - 1) / blk;     // 576
        hipLaunchKernelGGL(repack_weights_kernel, dim3(grid), dim3(blk), 0, stream,
                           w, pk);
    }
    // 2) main conv
    {
        dim3 grid(NW / TILE_W, NH / TILE_H, NB);  // (4, 64, 32)
        hipLaunchKernelGGL(conv_mfma_kernel, grid, dim3(256), 0, stream,
                           x, pk, out);
    }
}

// Round 2
// 316.409 us; speedup vs baseline: 3.1473x; 3.1473x over previous
//
#include <hip/hip_runtime.h>
#include <hip/hip_bf16.h>

// Grouped conv2d as implicit GEMM per group:
//   out[b*64+co][h][w] = sum_{ci,kh,kw} W[b*64+co][ci][kh][kw] * x[b*64+ci][h+kh-1][w+kw-1]
// bf16 MFMA (16x16x32), fp32 accumulate. K = tap-major (9 taps x 64 ci).
//
// R2 changes vs R1 (latency-bound at 1030us, 20% HBM):
//  - staging: branchless float4 loads (16B/lane), load-batched 4x6 chunks -> deep MLP
//  - A-fragments: 18-step (tap,kc) software pipeline, static 2-deep double buffer
//  - XCD-aware bijective block swizzle (halo L2 reuse)

typedef __bf16 bf16x8 __attribute__((ext_vector_type(8)));
typedef float  f32x4  __attribute__((ext_vector_type(4)));

#define NB 32
#define NH 256
#define NW 256
#define TILE_H 4
#define TILE_W 64
#define XROWS 6     // TILE_H + 2 (halo)
#define XCOLS 68    // TILE_W + 2, padded

// ---------------------------------------------------------------------------
// Repack weights into MFMA A-fragment order:
//   pk[((b*9+tap)*4+mt)*2+kc][lane][j]  (bf16, 16B per lane)
// value = W[b*64 + mt*16 + (lane&15)][kc*32 + (lane>>4)*8 + j][tap]
// ---------------------------------------------------------------------------
__global__ void repack_weights_kernel(const float* __restrict__ wsrc,
                                      __bf16* __restrict__ pk) {
    int t = blockIdx.x * blockDim.x + threadIdx.x;
    if (t >= NB * 9 * 4 * 2 * 64) return;
    int lane = t & 63;
    int r = t >> 6;
    int kc = r & 1;  r >>= 1;
    int mt = r & 3;  r >>= 2;
    int tap = r % 9;
    int b   = r / 9;
    int co  = b * 64 + mt * 16 + (lane & 15);
    int ci0 = kc * 32 + (lane >> 4) * 8;
    bf16x8 v;
#pragma unroll
    for (int j = 0; j < 8; ++j) {
        v[j] = (__bf16)wsrc[(co * 64 + ci0 + j) * 9 + tap];
    }
    *reinterpret_cast<bf16x8*>(pk + (size_t)t * 8) = v;
}

// ---------------------------------------------------------------------------
// Main conv kernel. Block = (group b, 4 output rows, 64 output cols).
// 4 waves; wave w owns output row h0+w, all 64 c_out, 64 cols (4 n-tiles).
// X tile staged in LDS as bf16, layout [r][c][ci], ci XOR-swizzled by (c&7)<<3.
// ---------------------------------------------------------------------------
__launch_bounds__(256, 3)
__global__ void conv_mfma_kernel(const float* __restrict__ x,
                                 const __bf16* __restrict__ pk,
                                 float* __restrict__ out) {
    __shared__ __align__(16) __bf16 xs[XROWS * XCOLS * 64];

    // XCD-aware bijective swizzle: 8192 blocks, 8 XCDs -> contiguous 1024-chunk per XCD
    const int orig = blockIdx.x;
    const int wg   = (orig & 7) * 1024 + (orig >> 3);
    const int b    = wg >> 8;            // 0..31
    const int by   = (wg >> 2) & 63;     // 0..63
    const int bx   = wg & 3;             // 0..3
    const int h0   = by * TILE_H;
    const int w0   = bx * TILE_W;

    const int tid  = threadIdx.x;
    const int wid  = tid >> 6;
    const int lane = tid & 63;

    const __bf16* pkb = pk + (size_t)b * 9 * 4096;

    // Preload A fragments for step 0 (tap0, kc0) before staging to hide latency
    bf16x8 af[2][4];
#pragma unroll
    for (int mt = 0; mt < 4; ++mt)
        af[0][mt] = *reinterpret_cast<const bf16x8*>(pkb + ((mt * 2) * 64 + lane) * 8);

    // ---- stage X halo tile: branchless, float4 main region ----
    {
        const int q  = tid & 15;        // float4 quad within 64 main cols
        const int sb = tid >> 4;        // segment base 0..15
#pragma unroll
        for (int kk = 0; kk < 4; ++kk) {
            f32x4 v[6];
#pragma unroll
            for (int j = 0; j < 6; ++j) {
                const int seg = sb + 16 * (kk * 6 + j);   // 0..383
                const int r   = seg >> 6;
                const int ci  = seg & 63;
                const int h   = h0 - 1 + r;
                const int hc  = min(max(h, 0), NH - 1);
                v[j] = *reinterpret_cast<const f32x4*>(
                    x + ((size_t)(b * 64 + ci) * NH + hc) * NW + w0 + q * 4);
                if (h != hc) v[j] = (f32x4){0.f, 0.f, 0.f, 0.f};
            }
#pragma unroll
            for (int j = 0; j < 6; ++j) {
                const int seg = sb + 16 * (kk * 6 + j);
                const int r   = seg >> 6;
                const int ci  = seg & 63;
#pragma unroll
                for (int e = 0; e < 4; ++e) {
                    const int c = q * 4 + 1 + e;
                    xs[(r * XCOLS + c) * 64 + (ci ^ ((c & 7) << 3))] = (__bf16)v[j][e];
                }
            }
        }
        // halo columns c=0 and c=65 (2 per (r,ci) segment): 768 scalars
#pragma unroll
        for (int k = 0; k < 3; ++k) {
            const int i    = tid + 256 * k;   // 0..767
            const int r    = i >> 7;
            const int rem  = i & 127;
            const int ci   = rem >> 1;
            const int side = rem & 1;
            const int c    = side ? 65 : 0;
            const int h    = h0 - 1 + r;
            const int w    = side ? (w0 + 64) : (w0 - 1);
            const int hc   = min(max(h, 0), NH - 1);
            const int wc   = min(max(w, 0), NW - 1);
            float f = x[((size_t)(b * 64 + ci) * NH + hc) * NW + wc];
            if (h != hc || w != wc) f = 0.f;
            xs[(r * XCOLS + c) * 64 + (ci ^ ((c & 7) << 3))] = (__bf16)f;
        }
    }

    f32x4 acc[4][4];   // [mt][q]
#pragma unroll
    for (int mt = 0; mt < 4; ++mt)
#pragma unroll
        for (int q = 0; q < 4; ++q)
            acc[mt][q] = (f32x4){0.f, 0.f, 0.f, 0.f};

    __syncthreads();

    const int nl   = lane & 15;
    const int kgrp = lane >> 4;       // 0..3

    // 18-step (tap,kc) K-loop, fully unrolled, 1-step A prefetch.
    // af parity index == step&1 == kc (compile-time under full unroll).
#pragma unroll
    for (int step = 0; step < 18; ++step) {
        const int tap = step >> 1;
        const int kc  = step & 1;
        if (step < 17) {
            const int ns   = step + 1;
            const int ntap = ns >> 1;
            const int nkc  = ns & 1;
#pragma unroll
            for (int mt = 0; mt < 4; ++mt)
                af[ns & 1][mt] = *reinterpret_cast<const bf16x8*>(
                    pkb + ntap * 4096 + ((mt * 2 + nkc) * 64 + lane) * 8);
        }
        const int kh = tap / 3;
        const int kw = tap - kh * 3;
        const int rowbase = (wid + kh) * XCOLS;
        const int ci0 = kc * 32 + kgrp * 8;
#pragma unroll
        for (int q = 0; q < 4; ++q) {
            const int c = q * 16 + nl + kw;    // 0..65
            bf16x8 bfv = *reinterpret_cast<const bf16x8*>(
                xs + (rowbase + c) * 64 + (ci0 ^ ((c & 7) << 3)));
#pragma unroll
            for (int mt = 0; mt < 4; ++mt)
                acc[mt][q] = __builtin_amdgcn_mfma_f32_16x16x32_bf16(
                    af[step & 1][mt], bfv, acc[mt][q], 0, 0, 0);
        }
    }

    // ---- epilogue: D lane layout col=lane&15, row=(lane>>4)*4+reg ----
    const int mrow = (lane >> 4) * 4;
    const int h = h0 + wid;
#pragma unroll
    for (int mt = 0; mt < 4; ++mt) {
#pragma unroll
        for (int q = 0; q < 4; ++q) {
            const int w = w0 + q * 16 + nl;
#pragma unroll
            for (int rg = 0; rg < 4; ++rg) {
                const int co = mt * 16 + mrow + rg;
                out[((size_t)(b * 64 + co) * NH + h) * NW + w] = acc[mt][q][rg];
            }
        }
    }
}

extern "C" void kernel_launch(void* const* d_in, const int* in_sizes, int n_in,
                              void* d_out, int out_size, void* d_ws, size_t ws_size,
                              hipStream_t stream) {
    const float* x = (const float*)d_in[0];     // [1, 32*64, 256, 256] fp32
    const float* w = (const float*)d_in[1];     // [2048, 64, 3, 3] fp32
    float* out = (float*)d_out;                 // [1, 2048, 256, 256] fp32
    __bf16* pk = (__bf16*)d_ws;                 // 2.25 MB repacked bf16 weights

    {
        int total = NB * 9 * 4 * 2 * 64;        // 147456
        int blk = 256;
        int grid = (total + blk - 1) / blk;     // 576
        hipLaunchKernelGGL(repack_weights_kernel, dim3(grid), dim3(blk), 0, stream,
                           w, pk);
    }
    {
        dim3 grid(8192);                        // 1D, swizzled in-kernel
        hipLaunchKernelGGL(conv_mfma_kernel, grid, dim3(256), 0, stream,
                           x, pk, out);
    }
}